// Round 1
// baseline (158.134 us; speedup 1.0000x reference)
//
#include <hip/hip_runtime.h>

// Problem constants (fixed by the reference)
#define NN   16
#define DD   3
#define HH   160
#define WW   160
#define MM   8
#define KK   10
#define PP   15
#define PM   7            // (P-1)/2
#define OUTH 146          // H - P + 1
#define OUTW 146
#define MK   (MM*KK)      // 80
#define HALFW 73          // OUTW/2
#define UNITS (OUTH*HALFW) // 10658 float2 units per plane

__global__ __launch_bounds__(256)
void fern_bits_kernel(const float* __restrict__ T,
                      const float* __restrict__ dx1,
                      const float* __restrict__ dx2,
                      const float* __restrict__ dy1,
                      const float* __restrict__ dy2,
                      const float* __restrict__ th,
                      const float* __restrict__ amb,
                      const int*   __restrict__ channels,
                      float* __restrict__ out)
{
    const int mk = blockIdx.y;       // 0..79
    const int n  = blockIdx.z;       // 0..15
    const int k  = mk % KK;
    const int m  = mk / KK;
    const int c  = channels[k];

    // Per-feature (block-uniform) parameters
    float a, f;
    a = dx1[mk]; f = floorf(a); const float fx1 = a - f; const int sx1 = PM + (int)f;
    a = dy1[mk]; f = floorf(a); const float fy1 = a - f; const int sy1 = PM + (int)f;
    a = dx2[mk]; f = floorf(a); const float fx2 = a - f; const int sx2 = PM + (int)f;
    a = dy2[mk]; f = floorf(a); const float fy2 = a - f; const int sy2 = PM + (int)f;
    const float thv = th[mk];
    const float pos = amb[(m*2 + 0)*KK + k];
    const float neg = amb[(m*2 + 1)*KK + k];
    const float scl = 1.0f / (pos - neg + 1e-29f);

    const float* __restrict__ Tp = T + (size_t)(n*DD + c) * (HH*WW);

    const int u = blockIdx.x * 256 + threadIdx.x;
    if (u >= UNITS) return;
    const int y = u / HALFW;
    const int x = (u - y * HALFW) * 2;   // even x; thread covers x and x+1

    // Sample 1: 3 columns x 2 rows around (sy1+y, sx1+x)
    float p1a, p1b;
    {
        const float* r = Tp + (sy1 + y) * WW + (sx1 + x);
        const float v0 = r[0],  v1 = r[1],    v2 = r[2];
        const float w0 = r[WW], w1 = r[WW+1], w2 = r[WW+2];
        const float t0 = v0 + fx1 * (v1 - v0);
        const float t1 = v1 + fx1 * (v2 - v1);
        const float b0 = w0 + fx1 * (w1 - w0);
        const float b1 = w1 + fx1 * (w2 - w1);
        p1a = t0 + fy1 * (b0 - t0);
        p1b = t1 + fy1 * (b1 - t1);
    }
    // Sample 2
    float p2a, p2b;
    {
        const float* r = Tp + (sy2 + y) * WW + (sx2 + x);
        const float v0 = r[0],  v1 = r[1],    v2 = r[2];
        const float w0 = r[WW], w1 = r[WW+1], w2 = r[WW+2];
        const float t0 = v0 + fx2 * (v1 - v0);
        const float t1 = v1 + fx2 * (v2 - v1);
        const float b0 = w0 + fx2 * (w1 - w0);
        const float b1 = w1 + fx2 * (w2 - w1);
        p2a = t0 + fy2 * (b0 - t0);
        p2b = t1 + fy2 * (b1 - t1);
    }

    float t0 = p1a - p2a; if (fabsf(t0) < 1e-5f) t0 = 0.0f;
    float t1 = p1b - p2b; if (fabsf(t1) < 1e-5f) t1 = 0.0f;

    const float o0 = fminf(fmaxf((t0 - thv - neg) * scl, 0.0f), 1.0f);
    const float o1 = fminf(fmaxf((t1 - thv - neg) * scl, 0.0f), 1.0f);

    const size_t oidx = ((size_t)(n * MK + mk) * OUTH + y) * OUTW + x;
    float2* dst = (float2*)(out + oidx);   // 8B-aligned: row stride 584B, x even
    *dst = make_float2(o0, o1);
}

extern "C" void kernel_launch(void* const* d_in, const int* in_sizes, int n_in,
                              void* d_out, int out_size, void* d_ws, size_t ws_size,
                              hipStream_t stream) {
    const float* T        = (const float*)d_in[0];
    const float* dx1      = (const float*)d_in[1];
    const float* dx2      = (const float*)d_in[2];
    const float* dy1      = (const float*)d_in[3];
    const float* dy2      = (const float*)d_in[4];
    const float* th       = (const float*)d_in[5];
    const float* amb      = (const float*)d_in[6];
    const int*   channels = (const int*)d_in[7];
    // d_in[8] = patch_size scalar (compile-time constant PP=15 here)
    float* out = (float*)d_out;

    dim3 grid((UNITS + 255) / 256, MK, NN);
    dim3 block(256, 1, 1);
    fern_bits_kernel<<<grid, block, 0, stream>>>(T, dx1, dx2, dy1, dy2, th, amb,
                                                 channels, out);
}